// Round 1
// baseline (516.933 us; speedup 1.0000x reference)
//
#include <hip/hip_runtime.h>

static constexpr int B_    = 64;
static constexpr int N_    = 2048;
static constexpr int DI_   = 8;
static constexpr int O_    = 32;
static constexpr int P_    = 16;
static constexpr int OP_   = O_ * P_;      // 512
static constexpr int NBLK_ = 256;
static constexpr int CHUNK_ = N_ / NBLK_;  // 8

// MODE 0: iter0 (uniform rw, scale 1/32 folded into v_kernel), no v_in, no rw_out
// MODE 1: pass with v_in (=v0), softmax, accumulate s
// MODE 2: MODE1 + write normalized rw to rw_out (final iteration, v_in = v0+v1)
template <int MODE, bool ATOMIC>
__global__ __launch_bounds__(512, 2)
void fused_pass(const float* __restrict__ x, const float* __restrict__ W,
                const float* __restrict__ v_in, float* __restrict__ s_out,
                float* __restrict__ rw_out) {
  __shared__ float x_lds[64 * 65];   // [rem=(n'*8+i)][b], stride 65 -> conflict-free
  __shared__ float a_lds[O_ * 64];   // [o][b]
  const int tid  = threadIdx.x;
  const int lane = tid & 63;         // lane == batch b
  const int wave = tid >> 6;         // 0..7
  const int o0   = wave * 4;         // wave owns o in [o0, o0+4)
  const int n0   = blockIdx.x * CHUNK_;

  // stage x[b][n0..n0+7][i] -> LDS (coalesced global, conflict-free LDS write)
  #pragma unroll
  for (int k = 0; k < 8; ++k) {
    int d = k * 512 + tid;
    int b = d >> 6, rem = d & 63;
    x_lds[rem * 65 + b] = x[b * (N_ * DI_) + n0 * DI_ + rem];
  }

  float v_reg[64];  // v_in[b=lane][o in wave quad][p]
  if (MODE != 0) {
    #pragma unroll
    for (int oo = 0; oo < 4; ++oo) {
      const float4* vp = (const float4*)(v_in + (size_t)lane * OP_ + (o0 + oo) * P_);
      #pragma unroll
      for (int q = 0; q < 4; ++q) {
        float4 t = vp[q];
        v_reg[oo * 16 + q * 4 + 0] = t.x;
        v_reg[oo * 16 + q * 4 + 1] = t.y;
        v_reg[oo * 16 + q * 4 + 2] = t.z;
        v_reg[oo * 16 + q * 4 + 3] = t.w;
      }
    }
  }

  float s_acc[64];
  #pragma unroll
  for (int q = 0; q < 64; ++q) s_acc[q] = 0.0f;

  __syncthreads();

  #pragma unroll 1
  for (int nn = 0; nn < CHUNK_; ++nn) {
    const int n = n0 + nn;

    float x_reg[8];
    #pragma unroll
    for (int i = 0; i < 8; ++i) x_reg[i] = x_lds[(nn * 8 + i) * 65 + lane];

    float e[32];
    float em[4];
    float rZ = 0.0f;

    if (MODE != 0) {
      // ---- pass A: a[o] = sum_p preds[o,p] * v[o,p]  (preds = W row . x) ----
      float a_oo[4];
      #pragma unroll
      for (int oo = 0; oo < 4; ++oo) {
        const int o_u = __builtin_amdgcn_readfirstlane(o0 + oo);  // wave-uniform -> s_load
        const float* wp = W + (size_t)(n * O_ + o_u) * (P_ * DI_);
        float a = 0.0f;
        #pragma unroll
        for (int p = 0; p < P_; ++p) {
          float pr = 0.0f;
          #pragma unroll
          for (int i = 0; i < DI_; ++i)
            pr = __builtin_fmaf(wp[p * DI_ + i], x_reg[i], pr);
          a = __builtin_fmaf(pr, v_reg[oo * 16 + p], a);
        }
        a_oo[oo] = a;
      }
      __syncthreads();  // previous n's a_lds readers done
      #pragma unroll
      for (int oo = 0; oo < 4; ++oo) a_lds[(o0 + oo) * 64 + lane] = a_oo[oo];
      __syncthreads();

      // ---- softmax over all 32 o, fully in-lane (b = lane) ----
      float m = -1e30f;
      #pragma unroll
      for (int o = 0; o < O_; ++o) {
        e[o] = a_lds[o * 64 + lane];
        m = fmaxf(m, e[o]);
      }
      float Z = 0.0f;
      #pragma unroll
      for (int o = 0; o < O_; ++o) {
        e[o] = __expf(e[o] - m);
        Z += e[o];
      }
      rZ = 1.0f / Z;
      #pragma unroll
      for (int oo = 0; oo < 4; ++oo)
        em[oo] = __expf(a_oo[oo] - m) * rZ;   // rw for this wave's o-quad
    }

    // ---- pass B: s[b,o,p] += rw[b,n,o] * preds[b,n,o,p]  (recompute preds) ----
    #pragma unroll
    for (int oo = 0; oo < 4; ++oo) {
      const int o_u = __builtin_amdgcn_readfirstlane(o0 + oo);
      const float* wp = W + (size_t)(n * O_ + o_u) * (P_ * DI_);
      const float sc = (MODE == 0) ? 1.0f : em[oo];
      #pragma unroll
      for (int p = 0; p < P_; ++p) {
        float pr = 0.0f;
        #pragma unroll
        for (int i = 0; i < DI_; ++i)
          pr = __builtin_fmaf(wp[p * DI_ + i], x_reg[i], pr);
        s_acc[oo * 16 + p] = __builtin_fmaf(sc, pr, s_acc[oo * 16 + p]);
      }
    }

    if (MODE == 2) {
      // final rw output, [b][n][o]: 128B contiguous per lane
      float* rp = rw_out + ((size_t)lane * N_ + n) * O_;
      #pragma unroll
      for (int o4 = 0; o4 < 8; ++o4) {
        float4 t;
        t.x = e[o4 * 4 + 0] * rZ;
        t.y = e[o4 * 4 + 1] * rZ;
        t.z = e[o4 * 4 + 2] * rZ;
        t.w = e[o4 * 4 + 3] * rZ;
        ((float4*)rp)[o4] = t;
      }
    }
  }

  // write block partial of s: layout [blk][q=o*16+p][b]  (coalesced per (o,p))
  if (ATOMIC) {
    #pragma unroll
    for (int oo = 0; oo < 4; ++oo)
      #pragma unroll
      for (int p = 0; p < P_; ++p)
        atomicAdd(&s_out[(size_t)(((o0 + oo) * 16 + p) * 64 + lane)],
                  s_acc[oo * 16 + p]);
  } else {
    float* sp = s_out + (size_t)blockIdx.x * (OP_ * 64);
    #pragma unroll
    for (int oo = 0; oo < 4; ++oo)
      #pragma unroll
      for (int p = 0; p < P_; ++p)
        sp[((o0 + oo) * 16 + p) * 64 + lane] = s_acc[oo * 16 + p];
  }
}

// reduce partials over nparts, squash, optionally add v_add (for vsum = v0+v1)
__global__ __launch_bounds__(1024)
void v_kernel(const float* __restrict__ spart, int nparts, float scale,
              const float* __restrict__ v_add, float* __restrict__ v_out) {
  __shared__ float sq[P_ * 64];
  const int t = threadIdx.x;
  const int b = t & 63;
  const int p = t >> 6;
  const int o = blockIdx.x;
  const int q = o * P_ + p;
  float acc = 0.0f;
  for (int k = 0; k < nparts; ++k)
    acc += spart[(size_t)k * (OP_ * 64) + q * 64 + b];
  acc *= scale;
  sq[p * 64 + b] = acc * acc;
  __syncthreads();
  float s2 = 0.0f;
  #pragma unroll
  for (int pp = 0; pp < P_; ++pp) s2 += sq[pp * 64 + b];
  float sc = (s2 / (1.0f + s2)) / sqrtf(s2 + 1e-7f);
  float v = acc * sc;
  const int idx = b * OP_ + q;   // v layout [b][o][p]
  v_out[idx] = v + (v_add ? v_add[idx] : 0.0f);
}

extern "C" void kernel_launch(void* const* d_in, const int* in_sizes, int n_in,
                              void* d_out, int out_size, void* d_ws, size_t ws_size,
                              hipStream_t stream) {
  (void)in_sizes; (void)n_in; (void)out_size;
  const float* x = (const float*)d_in[0];
  const float* W = (const float*)d_in[1];
  float* out_v  = (float*)d_out;                       // [64][32][16]
  float* out_rw = out_v + (size_t)B_ * O_ * P_;        // [64][2048][32]
  float* vws   = (float*)d_ws;                         // v0
  float* vsum  = vws + B_ * O_ * P_;                   // v0+v1
  float* spart = vsum + B_ * O_ * P_;

  const size_t base_bytes = (size_t)2 * B_ * O_ * P_ * sizeof(float);
  const size_t part_bytes = (size_t)NBLK_ * OP_ * 64 * sizeof(float);
  const bool big = ws_size >= base_bytes + part_bytes;

  dim3 gF(NBLK_), bF(512), gV(O_), bV(1024);
  if (big) {
    fused_pass<0, false><<<gF, bF, 0, stream>>>(x, W, nullptr, spart, nullptr);
    v_kernel<<<gV, bV, 0, stream>>>(spart, NBLK_, 1.0f / 32.0f, nullptr, vws);
    fused_pass<1, false><<<gF, bF, 0, stream>>>(x, W, vws, spart, nullptr);
    v_kernel<<<gV, bV, 0, stream>>>(spart, NBLK_, 1.0f, vws, vsum);
    fused_pass<2, false><<<gF, bF, 0, stream>>>(x, W, vsum, spart, out_rw);
    v_kernel<<<gV, bV, 0, stream>>>(spart, NBLK_, 1.0f, nullptr, out_v);
  } else {
    const size_t sbytes = (size_t)OP_ * 64 * sizeof(float);
    hipMemsetAsync(spart, 0, sbytes, stream);
    fused_pass<0, true><<<gF, bF, 0, stream>>>(x, W, nullptr, spart, nullptr);
    v_kernel<<<gV, bV, 0, stream>>>(spart, 1, 1.0f / 32.0f, nullptr, vws);
    hipMemsetAsync(spart, 0, sbytes, stream);
    fused_pass<1, true><<<gF, bF, 0, stream>>>(x, W, vws, spart, nullptr);
    v_kernel<<<gV, bV, 0, stream>>>(spart, 1, 1.0f, vws, vsum);
    hipMemsetAsync(spart, 0, sbytes, stream);
    fused_pass<2, true><<<gF, bF, 0, stream>>>(x, W, vsum, spart, out_rw);
    v_kernel<<<gV, bV, 0, stream>>>(spart, 1, 1.0f, nullptr, out_v);
  }
}

// Round 2
// 421.476 us; speedup vs baseline: 1.2265x; 1.2265x over previous
//
#include <hip/hip_runtime.h>

static constexpr int B_    = 64;
static constexpr int N_    = 2048;
static constexpr int DI_   = 8;
static constexpr int O_    = 32;
static constexpr int P_    = 16;
static constexpr int OP_   = O_ * P_;      // 512
static constexpr int NBLK_ = 256;
static constexpr int CHUNK_ = N_ / NBLK_;  // 8

__device__ __forceinline__ float dot8(const float* __restrict__ wp,
                                      const float4& xa, const float4& xb) {
  float pr = wp[0] * xa.x;
  pr = __builtin_fmaf(wp[1], xa.y, pr);
  pr = __builtin_fmaf(wp[2], xa.z, pr);
  pr = __builtin_fmaf(wp[3], xa.w, pr);
  pr = __builtin_fmaf(wp[4], xb.x, pr);
  pr = __builtin_fmaf(wp[5], xb.y, pr);
  pr = __builtin_fmaf(wp[6], xb.z, pr);
  pr = __builtin_fmaf(wp[7], xb.w, pr);
  return pr;
}

// MODE 0: iter0 (uniform rw; 1/32 folded into v_kernel scale). Phase B only.
// MODE 1: phase A (logits vs v_in) + softmax + phase B.
// MODE 2: MODE1 + write normalized rw to rw_out (v_in = v0+v1 by linearity).
template <int MODE, bool ATOMIC>
__global__ __launch_bounds__(1024, 4)
void fused_pass(const float* __restrict__ x, const float* __restrict__ W,
                const float* __restrict__ v_in, float* __restrict__ s_out,
                float* __restrict__ rw_out) {
  __shared__ float x_lds[64 * 65];            // [rem=(nn*8+i)][b], pad 65
  __shared__ float a_lds[CHUNK_ * O_ * B_];   // 64 KB: [nn][o][b] logits -> rw
  const int tid  = threadIdx.x;
  const int lane = tid & 63;                  // lane == batch b
  const int wave = tid >> 6;                  // 0..15
  const int n0   = blockIdx.x * CHUNK_;

  // stage x[b][n0..n0+7][i] -> LDS (coalesced 256B/wave; write banks spread by rem+b)
  #pragma unroll
  for (int k = 0; k < 4; ++k) {
    int d = k * 1024 + tid;
    int b = d >> 6, rem = d & 63;
    x_lds[rem * 65 + b] = x[b * (N_ * DI_) + n0 * DI_ + rem];
  }
  __syncthreads();

  if (MODE != 0) {
    // ---- phase A: a[nn][o][b] = <preds(b,n,o,:), v(b,o,:)> ----
    #pragma unroll 1
    for (int oo = 0; oo < 2; ++oo) {
      const int o   = wave * 2 + oo;
      const int o_u = __builtin_amdgcn_readfirstlane(o);
      const float4* vp = (const float4*)(v_in + (size_t)lane * OP_ + o * P_);
      float4 v0 = vp[0], v1 = vp[1], v2 = vp[2], v3 = vp[3];
      #pragma unroll 2
      for (int nn = 0; nn < CHUNK_; ++nn) {
        const float* wp = W + (size_t)((n0 + nn) * O_ + o_u) * (P_ * DI_);
        const float* xp = &x_lds[nn * 8 * 65 + lane];
        float4 xa, xb;
        xa.x = xp[0];   xa.y = xp[65];  xa.z = xp[130]; xa.w = xp[195];
        xb.x = xp[260]; xb.y = xp[325]; xb.z = xp[390]; xb.w = xp[455];
        float a;
        a = dot8(wp +   0, xa, xb) * v0.x;
        a = __builtin_fmaf(dot8(wp +   8, xa, xb), v0.y, a);
        a = __builtin_fmaf(dot8(wp +  16, xa, xb), v0.z, a);
        a = __builtin_fmaf(dot8(wp +  24, xa, xb), v0.w, a);
        a = __builtin_fmaf(dot8(wp +  32, xa, xb), v1.x, a);
        a = __builtin_fmaf(dot8(wp +  40, xa, xb), v1.y, a);
        a = __builtin_fmaf(dot8(wp +  48, xa, xb), v1.z, a);
        a = __builtin_fmaf(dot8(wp +  56, xa, xb), v1.w, a);
        a = __builtin_fmaf(dot8(wp +  64, xa, xb), v2.x, a);
        a = __builtin_fmaf(dot8(wp +  72, xa, xb), v2.y, a);
        a = __builtin_fmaf(dot8(wp +  80, xa, xb), v2.z, a);
        a = __builtin_fmaf(dot8(wp +  88, xa, xb), v2.w, a);
        a = __builtin_fmaf(dot8(wp +  96, xa, xb), v3.x, a);
        a = __builtin_fmaf(dot8(wp + 104, xa, xb), v3.y, a);
        a = __builtin_fmaf(dot8(wp + 112, xa, xb), v3.z, a);
        a = __builtin_fmaf(dot8(wp + 120, xa, xb), v3.w, a);
        a_lds[(nn * O_ + o) * B_ + lane] = a;
      }
    }
    __syncthreads();

    // ---- softmax over o (in-lane; wave nn handles its row) ----
    if (wave < CHUNK_) {
      const int nn = wave;
      float* ap = &a_lds[nn * O_ * B_ + lane];
      float m = -3.0e38f;
      #pragma unroll
      for (int o = 0; o < O_; ++o) m = fmaxf(m, ap[o * B_]);
      float Z = 0.0f;
      #pragma unroll
      for (int o = 0; o < O_; ++o) Z += __expf(ap[o * B_] - m);
      float rZ = 1.0f / Z;
      if (MODE == 2) {
        float* rp = rw_out + ((size_t)lane * N_ + (n0 + nn)) * O_;
        #pragma unroll
        for (int o4 = 0; o4 < 8; ++o4) {
          float4 t;
          t.x = __expf(ap[(o4 * 4 + 0) * B_] - m) * rZ;
          t.y = __expf(ap[(o4 * 4 + 1) * B_] - m) * rZ;
          t.z = __expf(ap[(o4 * 4 + 2) * B_] - m) * rZ;
          t.w = __expf(ap[(o4 * 4 + 3) * B_] - m) * rZ;
          ap[(o4 * 4 + 0) * B_] = t.x;
          ap[(o4 * 4 + 1) * B_] = t.y;
          ap[(o4 * 4 + 2) * B_] = t.z;
          ap[(o4 * 4 + 3) * B_] = t.w;
          ((float4*)rp)[o4] = t;
        }
      } else {
        #pragma unroll
        for (int o = 0; o < O_; ++o) ap[o * B_] = __expf(ap[o * B_] - m) * rZ;
      }
    }
    __syncthreads();
  }

  // ---- phase B: s[b,o,p] += rw * preds (recompute preds) ----
  #pragma unroll 1
  for (int oo = 0; oo < 2; ++oo) {
    const int o   = wave * 2 + oo;
    const int o_u = __builtin_amdgcn_readfirstlane(o);
    float4 s0 = {0,0,0,0}, s1 = {0,0,0,0}, s2 = {0,0,0,0}, s3 = {0,0,0,0};
    #pragma unroll 2
    for (int nn = 0; nn < CHUNK_; ++nn) {
      const float* wp = W + (size_t)((n0 + nn) * O_ + o_u) * (P_ * DI_);
      const float* xp = &x_lds[nn * 8 * 65 + lane];
      float4 xa, xb;
      xa.x = xp[0];   xa.y = xp[65];  xa.z = xp[130]; xa.w = xp[195];
      xb.x = xp[260]; xb.y = xp[325]; xb.z = xp[390]; xb.w = xp[455];
      const float sc = (MODE == 0) ? 1.0f : a_lds[(nn * O_ + o) * B_ + lane];
      s0.x = __builtin_fmaf(sc, dot8(wp +   0, xa, xb), s0.x);
      s0.y = __builtin_fmaf(sc, dot8(wp +   8, xa, xb), s0.y);
      s0.z = __builtin_fmaf(sc, dot8(wp +  16, xa, xb), s0.z);
      s0.w = __builtin_fmaf(sc, dot8(wp +  24, xa, xb), s0.w);
      s1.x = __builtin_fmaf(sc, dot8(wp +  32, xa, xb), s1.x);
      s1.y = __builtin_fmaf(sc, dot8(wp +  40, xa, xb), s1.y);
      s1.z = __builtin_fmaf(sc, dot8(wp +  48, xa, xb), s1.z);
      s1.w = __builtin_fmaf(sc, dot8(wp +  56, xa, xb), s1.w);
      s2.x = __builtin_fmaf(sc, dot8(wp +  64, xa, xb), s2.x);
      s2.y = __builtin_fmaf(sc, dot8(wp +  72, xa, xb), s2.y);
      s2.z = __builtin_fmaf(sc, dot8(wp +  80, xa, xb), s2.z);
      s2.w = __builtin_fmaf(sc, dot8(wp +  88, xa, xb), s2.w);
      s3.x = __builtin_fmaf(sc, dot8(wp +  96, xa, xb), s3.x);
      s3.y = __builtin_fmaf(sc, dot8(wp + 104, xa, xb), s3.y);
      s3.z = __builtin_fmaf(sc, dot8(wp + 112, xa, xb), s3.z);
      s3.w = __builtin_fmaf(sc, dot8(wp + 120, xa, xb), s3.w);
    }
    if (ATOMIC) {
      float* sp = s_out + (size_t)(o * P_) * B_ + lane;
      atomicAdd(&sp[ 0 * B_], s0.x); atomicAdd(&sp[ 1 * B_], s0.y);
      atomicAdd(&sp[ 2 * B_], s0.z); atomicAdd(&sp[ 3 * B_], s0.w);
      atomicAdd(&sp[ 4 * B_], s1.x); atomicAdd(&sp[ 5 * B_], s1.y);
      atomicAdd(&sp[ 6 * B_], s1.z); atomicAdd(&sp[ 7 * B_], s1.w);
      atomicAdd(&sp[ 8 * B_], s2.x); atomicAdd(&sp[ 9 * B_], s2.y);
      atomicAdd(&sp[10 * B_], s2.z); atomicAdd(&sp[11 * B_], s2.w);
      atomicAdd(&sp[12 * B_], s3.x); atomicAdd(&sp[13 * B_], s3.y);
      atomicAdd(&sp[14 * B_], s3.z); atomicAdd(&sp[15 * B_], s3.w);
    } else {
      float* sp = s_out + (size_t)blockIdx.x * (OP_ * B_) + (size_t)(o * P_) * B_ + lane;
      sp[ 0 * B_] = s0.x; sp[ 1 * B_] = s0.y; sp[ 2 * B_] = s0.z; sp[ 3 * B_] = s0.w;
      sp[ 4 * B_] = s1.x; sp[ 5 * B_] = s1.y; sp[ 6 * B_] = s1.z; sp[ 7 * B_] = s1.w;
      sp[ 8 * B_] = s2.x; sp[ 9 * B_] = s2.y; sp[10 * B_] = s2.z; sp[11 * B_] = s2.w;
      sp[12 * B_] = s3.x; sp[13 * B_] = s3.y; sp[14 * B_] = s3.z; sp[15 * B_] = s3.w;
    }
  }
}

// reduce partials over nparts, squash, optionally add v_add (for vsum = v0+v1)
__global__ __launch_bounds__(1024)
void v_kernel(const float* __restrict__ spart, int nparts, float scale,
              const float* __restrict__ v_add, float* __restrict__ v_out) {
  __shared__ float sq[P_ * 64];
  const int t = threadIdx.x;
  const int b = t & 63;
  const int p = t >> 6;
  const int o = blockIdx.x;
  const int q = o * P_ + p;
  float acc = 0.0f;
  for (int k = 0; k < nparts; ++k)
    acc += spart[(size_t)k * (OP_ * 64) + q * 64 + b];
  acc *= scale;
  sq[p * 64 + b] = acc * acc;
  __syncthreads();
  float s2 = 0.0f;
  #pragma unroll
  for (int pp = 0; pp < P_; ++pp) s2 += sq[pp * 64 + b];
  float sc = (s2 / (1.0f + s2)) / sqrtf(s2 + 1e-7f);
  float v = acc * sc;
  const int idx = b * OP_ + q;   // v layout [b][o][p]
  v_out[idx] = v + (v_add ? v_add[idx] : 0.0f);
}

extern "C" void kernel_launch(void* const* d_in, const int* in_sizes, int n_in,
                              void* d_out, int out_size, void* d_ws, size_t ws_size,
                              hipStream_t stream) {
  (void)in_sizes; (void)n_in; (void)out_size;
  const float* x = (const float*)d_in[0];
  const float* W = (const float*)d_in[1];
  float* out_v  = (float*)d_out;                       // [64][32][16]
  float* out_rw = out_v + (size_t)B_ * O_ * P_;        // [64][2048][32]
  float* vws   = (float*)d_ws;                         // v0
  float* vsum  = vws + B_ * O_ * P_;                   // v0+v1
  float* spart = vsum + B_ * O_ * P_;

  const size_t base_bytes = (size_t)2 * B_ * O_ * P_ * sizeof(float);
  const size_t part_bytes = (size_t)NBLK_ * OP_ * 64 * sizeof(float);
  const bool big = ws_size >= base_bytes + part_bytes;

  dim3 gF(NBLK_), bF(1024), gV(O_), bV(1024);
  if (big) {
    fused_pass<0, false><<<gF, bF, 0, stream>>>(x, W, nullptr, spart, nullptr);
    v_kernel<<<gV, bV, 0, stream>>>(spart, NBLK_, 1.0f / 32.0f, nullptr, vws);
    fused_pass<1, false><<<gF, bF, 0, stream>>>(x, W, vws, spart, nullptr);
    v_kernel<<<gV, bV, 0, stream>>>(spart, NBLK_, 1.0f, vws, vsum);
    fused_pass<2, false><<<gF, bF, 0, stream>>>(x, W, vsum, spart, out_rw);
    v_kernel<<<gV, bV, 0, stream>>>(spart, NBLK_, 1.0f, nullptr, out_v);
  } else {
    const size_t sbytes = (size_t)OP_ * 64 * sizeof(float);
    hipMemsetAsync(spart, 0, sbytes, stream);
    fused_pass<0, true><<<gF, bF, 0, stream>>>(x, W, nullptr, spart, nullptr);
    v_kernel<<<gV, bV, 0, stream>>>(spart, 1, 1.0f / 32.0f, nullptr, vws);
    hipMemsetAsync(spart, 0, sbytes, stream);
    fused_pass<1, true><<<gF, bF, 0, stream>>>(x, W, vws, spart, nullptr);
    v_kernel<<<gV, bV, 0, stream>>>(spart, 1, 1.0f, vws, vsum);
    hipMemsetAsync(spart, 0, sbytes, stream);
    fused_pass<2, true><<<gF, bF, 0, stream>>>(x, W, vsum, spart, out_rw);
    v_kernel<<<gV, bV, 0, stream>>>(spart, 1, 1.0f, nullptr, out_v);
  }
}